// Round 1
// baseline (443.331 us; speedup 1.0000x reference)
//
#include <hip/hip_runtime.h>

#define N_NODES 50000
#define N_EDGES 800000
#define D 64
#define CAP 64

typedef float vf4 __attribute__((ext_vector_type(4)));

// ---------------- K1: fused score + bucket build ----------------
// 1 thread per edge. e is read in *sequential* edge order (the only 200+MB
// stream in the problem, now at full streaming efficiency instead of the old
// k2's random bucket-order 256B reads). h_src row is a gather from a
// L2/L3-resident 12.8MB array. Slot payload carries {src, bits(exp(dot))} so
// the aggregation kernel never touches e and never recomputes the score.
__global__ __launch_bounds__(256) void k1_score_bucket(
    const vf4* __restrict__ h_src4, const vf4* __restrict__ e4,
    const int* __restrict__ src, const int* __restrict__ dst,
    int* __restrict__ count, int2* __restrict__ slots) {
    int i = blockIdx.x * 256 + threadIdx.x;   // grid sized exactly
    int s = src[i];
    int d = dst[i];
    const vf4* u  = h_src4 + (size_t)s * 16;
    const vf4* ev = e4 + (size_t)i * 16;
    vf4 dacc = {0.f, 0.f, 0.f, 0.f};          // 4-way split accumulator
    #pragma unroll
    for (int k = 0; k < 16; ++k) {
        vf4 a = u[k];
        vf4 bb = ev[k];
        dacc += a * bb;
    }
    float w = __expf(dacc[0] + dacc[1] + dacc[2] + dacc[3]);
    int pos = atomicAdd(&count[d], 1);
    if (pos < CAP)
        slots[(size_t)d * CAP + pos] = make_int2(s, __float_as_int(w));
}

// ---------------- K2: aggregate only ----------------
// 16 lanes per node, 16 nodes per block. Inner loop per edge is now just:
// 2 shfl broadcasts (src, w) + one cached 16B h_src gather + 4 FMA.
// Padding lanes carry w-bits == 0 -> wj == 0.0f, so pads contribute exactly
// zero with no predicate (their sj==0 gather hits a hot line). Higher
// occupancy (6 waves/EU -> 24 waves/CU) to hide the gather latency.
__global__ __launch_bounds__(256, 6) void k2_agg(
    const vf4* __restrict__ h_src4,
    const int* __restrict__ count, const int2* __restrict__ slots,
    vf4* __restrict__ h_sum4) {
    int t = threadIdx.x;
    int node = blockIdx.x * 16 + (t >> 4);         // 50000/16 = 3125 exact
    int l16 = t & 15;
    int cnt = count[node];
    cnt = cnt < CAP ? cnt : CAP;
    const int2* row = slots + (size_t)node * CAP;
    vf4 acc = {0.f, 0.f, 0.f, 0.f};
    float dsum = 0.f;
    int2 se = make_int2(0, 0);                     // batch-0 slot prefetch
    if (l16 < cnt) se = row[l16];
    for (int base = 0; base < cnt; base += 16) {
        int2 cur = se;
        int nxt = base + 16;
        se = make_int2(0, 0);
        if (nxt + l16 < cnt) se = row[nxt + l16];  // prefetch next batch
        #pragma unroll
        for (int j = 0; j < 16; ++j) {
            int sj = __shfl(cur.x, j, 16);
            float wj = __int_as_float(__shfl(cur.y, j, 16));
            vf4 u = h_src4[(size_t)sj * 16 + l16];
            acc += wj * u;
            dsum += wj;                            // same value in all 16 lanes
        }
    }
    float inv = (cnt > 0) ? 1.f / dsum : 0.f;
    acc *= inv;
    h_sum4[(size_t)node * 16 + l16] = acc;
}

// ---------------- K3: out = [h_dst | h_sum] @ W^T + b ----------------
// Wl padded to stride 65: bank = (65k+o)%32 = (k+o)%32 -> conflict-free for
// both the transpose fill (lanes vary k) and the epilogue read (lanes vary o).
__global__ __launch_bounds__(256) void k3_linear(
    const vf4* __restrict__ h_dst4, const vf4* __restrict__ h_sum4,
    const float* __restrict__ W, const float* __restrict__ b,
    float* __restrict__ out) {
    __shared__ float Wl[128 * 65];                 // transposed: Wl[k*65+o]
    __shared__ __align__(16) float ht[16][132];
    int t = threadIdx.x;
    for (int i = t; i < 128 * 64; i += 256) {
        int o = i >> 7, k = i & 127;               // W is [64][128] row-major
        Wl[k * 65 + o] = W[i];
    }
    int node0 = blockIdx.x * 16;
    {
        int n = t >> 4;
        int l16 = t & 15;
        int node = node0 + n;
        vf4 hd = h_dst4[(size_t)node * 16 + l16];
        vf4 hs = h_sum4[(size_t)node * 16 + l16];
        *(vf4*)&ht[n][l16 * 4] = hd;
        *(vf4*)&ht[n][64 + l16 * 4] = hs;
    }
    __syncthreads();

    int o = t & 63;
    int g = t >> 6;                                // nodes g*4 .. g*4+3
    float bias = b[o];
    float a0 = bias, a1 = bias, a2 = bias, a3 = bias;
    const float* h0 = &ht[g * 4 + 0][0];
    const float* h1 = &ht[g * 4 + 1][0];
    const float* h2 = &ht[g * 4 + 2][0];
    const float* h3 = &ht[g * 4 + 3][0];
    #pragma unroll
    for (int k = 0; k < 128; k += 4) {
        float w0 = Wl[(k + 0) * 65 + o];
        float w1 = Wl[(k + 1) * 65 + o];
        float w2 = Wl[(k + 2) * 65 + o];
        float w3 = Wl[(k + 3) * 65 + o];
        vf4 p0 = *(const vf4*)&h0[k];
        vf4 p1 = *(const vf4*)&h1[k];
        vf4 p2 = *(const vf4*)&h2[k];
        vf4 p3 = *(const vf4*)&h3[k];
        a0 += p0[0]*w0 + p0[1]*w1 + p0[2]*w2 + p0[3]*w3;
        a1 += p1[0]*w0 + p1[1]*w1 + p1[2]*w2 + p1[3]*w3;
        a2 += p2[0]*w0 + p2[1]*w1 + p2[2]*w2 + p2[3]*w3;
        a3 += p3[0]*w0 + p3[1]*w1 + p3[2]*w2 + p3[3]*w3;
    }
    out[(size_t)(node0 + g * 4 + 0) * 64 + o] = a0;
    out[(size_t)(node0 + g * 4 + 1) * 64 + o] = a1;
    out[(size_t)(node0 + g * 4 + 2) * 64 + o] = a2;
    out[(size_t)(node0 + g * 4 + 3) * 64 + o] = a3;
}

extern "C" void kernel_launch(void* const* d_in, const int* in_sizes, int n_in,
                              void* d_out, int out_size, void* d_ws, size_t ws_size,
                              hipStream_t stream) {
    const float* h_src = (const float*)d_in[0];
    const float* h_dst = (const float*)d_in[1];
    const float* e     = (const float*)d_in[2];
    const int*   src   = (const int*)d_in[3];
    const int*   dst   = (const int*)d_in[4];
    const float* W     = (const float*)d_in[5];
    const float* b     = (const float*)d_in[6];
    float* out = (float*)d_out;

    // workspace: count[N] | slots[N*CAP int2] | h_sum[N*64 f32]
    auto align256 = [](size_t x) { return (x + 255) & ~(size_t)255; };
    char* ws = (char*)d_ws;
    int*  count = (int*)ws;
    int2* slots = (int2*)(ws + align256((size_t)N_NODES * 4));
    float* h_sum = (float*)(ws + align256((size_t)N_NODES * 4)
                               + align256((size_t)N_NODES * CAP * 8));

    hipMemsetAsync(count, 0, (size_t)N_NODES * 4, stream);

    k1_score_bucket<<<N_EDGES / 256, 256, 0, stream>>>(
        (const vf4*)h_src, (const vf4*)e, src, dst, count, slots);
    k2_agg<<<N_NODES / 16, 256, 0, stream>>>(
        (const vf4*)h_src, count, slots, (vf4*)h_sum);
    k3_linear<<<(N_NODES + 15) / 16, 256, 0, stream>>>(
        (const vf4*)h_dst, (const vf4*)h_sum, W, b, out);
}

// Round 2
// 380.761 us; speedup vs baseline: 1.1643x; 1.1643x over previous
//
#include <hip/hip_runtime.h>

#define N_NODES 50000
#define N_EDGES 800000
#define D 64
#define CAP 64

typedef float vf4 __attribute__((ext_vector_type(4)));

// ---------------- K1: fused score + bucket build ----------------
// 16 lanes per edge, 16 edges per block. Lane l reads e4[i*16+l]: each
// quarter-wave issues ONE dwordx4 covering 256 contiguous bytes, and
// consecutive groups cover consecutive edges -> the 204.8MB e stream is
// fully coalesced AND sequential (the round-1 per-thread-row version
// touched 64 lines per load instruction -> 16x transaction amplification,
// 24% of peak). h_src row gather: coalesced 256B row, random row, L2/L3-
// resident. Dot = 4 FMA + 4-step shfl_xor tree; lane 0 does atomic + 8B
// slot write {src, bits(exp(dot))}.
__global__ __launch_bounds__(256) void k1_score_bucket(
    const vf4* __restrict__ h_src4, const vf4* __restrict__ e4,
    const int* __restrict__ src, const int* __restrict__ dst,
    int* __restrict__ count, int2* __restrict__ slots) {
    int t = threadIdx.x;
    int i = blockIdx.x * 16 + (t >> 4);        // 800000/16 = 50000 blocks exact
    int l16 = t & 15;
    int s = src[i];                            // same addr within group: broadcast
    vf4 u  = h_src4[(size_t)s * 16 + l16];
    vf4 ev = e4[(size_t)i * 16 + l16];
    float p = u[0]*ev[0] + u[1]*ev[1] + u[2]*ev[2] + u[3]*ev[3];
    p += __shfl_xor(p, 1, 16);
    p += __shfl_xor(p, 2, 16);
    p += __shfl_xor(p, 4, 16);
    p += __shfl_xor(p, 8, 16);
    if (l16 == 0) {
        int d = dst[i];
        float w = __expf(p);
        int pos = atomicAdd(&count[d], 1);
        if (pos < CAP)
            slots[(size_t)d * CAP + pos] = make_int2(s, __float_as_int(w));
    }
}

// ---------------- K2: aggregate only ----------------
// 16 lanes per node, 16 nodes per block. Inner loop per edge: 2 shfl
// broadcasts (src, w) + one cached 16B h_src gather + 4 FMA. Padding lanes
// carry w-bits == 0 -> wj == 0.0f, so pads contribute exactly zero with no
// predicate. 6 waves/EU to hide the gather latency.
__global__ __launch_bounds__(256, 6) void k2_agg(
    const vf4* __restrict__ h_src4,
    const int* __restrict__ count, const int2* __restrict__ slots,
    vf4* __restrict__ h_sum4) {
    int t = threadIdx.x;
    int node = blockIdx.x * 16 + (t >> 4);         // 50000/16 = 3125 exact
    int l16 = t & 15;
    int cnt = count[node];
    cnt = cnt < CAP ? cnt : CAP;
    const int2* row = slots + (size_t)node * CAP;
    vf4 acc = {0.f, 0.f, 0.f, 0.f};
    float dsum = 0.f;
    int2 se = make_int2(0, 0);                     // batch-0 slot prefetch
    if (l16 < cnt) se = row[l16];
    for (int base = 0; base < cnt; base += 16) {
        int2 cur = se;
        int nxt = base + 16;
        se = make_int2(0, 0);
        if (nxt + l16 < cnt) se = row[nxt + l16];  // prefetch next batch
        #pragma unroll
        for (int j = 0; j < 16; ++j) {
            int sj = __shfl(cur.x, j, 16);
            float wj = __int_as_float(__shfl(cur.y, j, 16));
            vf4 u = h_src4[(size_t)sj * 16 + l16];
            acc += wj * u;
            dsum += wj;                            // same value in all 16 lanes
        }
    }
    float inv = (cnt > 0) ? 1.f / dsum : 0.f;
    acc *= inv;
    h_sum4[(size_t)node * 16 + l16] = acc;
}

// ---------------- K3: out = [h_dst | h_sum] @ W^T + b ----------------
// Wl padded to stride 65: bank = (65k+o)%32 = (k+o)%32 -> conflict-free for
// both the transpose fill (lanes vary k) and the epilogue read (lanes vary o).
__global__ __launch_bounds__(256) void k3_linear(
    const vf4* __restrict__ h_dst4, const vf4* __restrict__ h_sum4,
    const float* __restrict__ W, const float* __restrict__ b,
    float* __restrict__ out) {
    __shared__ float Wl[128 * 65];                 // transposed: Wl[k*65+o]
    __shared__ __align__(16) float ht[16][132];
    int t = threadIdx.x;
    for (int i = t; i < 128 * 64; i += 256) {
        int o = i >> 7, k = i & 127;               // W is [64][128] row-major
        Wl[k * 65 + o] = W[i];
    }
    int node0 = blockIdx.x * 16;
    {
        int n = t >> 4;
        int l16 = t & 15;
        int node = node0 + n;
        vf4 hd = h_dst4[(size_t)node * 16 + l16];
        vf4 hs = h_sum4[(size_t)node * 16 + l16];
        *(vf4*)&ht[n][l16 * 4] = hd;
        *(vf4*)&ht[n][64 + l16 * 4] = hs;
    }
    __syncthreads();

    int o = t & 63;
    int g = t >> 6;                                // nodes g*4 .. g*4+3
    float bias = b[o];
    float a0 = bias, a1 = bias, a2 = bias, a3 = bias;
    const float* h0 = &ht[g * 4 + 0][0];
    const float* h1 = &ht[g * 4 + 1][0];
    const float* h2 = &ht[g * 4 + 2][0];
    const float* h3 = &ht[g * 4 + 3][0];
    #pragma unroll
    for (int k = 0; k < 128; k += 4) {
        float w0 = Wl[(k + 0) * 65 + o];
        float w1 = Wl[(k + 1) * 65 + o];
        float w2 = Wl[(k + 2) * 65 + o];
        float w3 = Wl[(k + 3) * 65 + o];
        vf4 p0 = *(const vf4*)&h0[k];
        vf4 p1 = *(const vf4*)&h1[k];
        vf4 p2 = *(const vf4*)&h2[k];
        vf4 p3 = *(const vf4*)&h3[k];
        a0 += p0[0]*w0 + p0[1]*w1 + p0[2]*w2 + p0[3]*w3;
        a1 += p1[0]*w0 + p1[1]*w1 + p1[2]*w2 + p1[3]*w3;
        a2 += p2[0]*w0 + p2[1]*w1 + p2[2]*w2 + p2[3]*w3;
        a3 += p3[0]*w0 + p3[1]*w1 + p3[2]*w2 + p3[3]*w3;
    }
    out[(size_t)(node0 + g * 4 + 0) * 64 + o] = a0;
    out[(size_t)(node0 + g * 4 + 1) * 64 + o] = a1;
    out[(size_t)(node0 + g * 4 + 2) * 64 + o] = a2;
    out[(size_t)(node0 + g * 4 + 3) * 64 + o] = a3;
}

extern "C" void kernel_launch(void* const* d_in, const int* in_sizes, int n_in,
                              void* d_out, int out_size, void* d_ws, size_t ws_size,
                              hipStream_t stream) {
    const float* h_src = (const float*)d_in[0];
    const float* h_dst = (const float*)d_in[1];
    const float* e     = (const float*)d_in[2];
    const int*   src   = (const int*)d_in[3];
    const int*   dst   = (const int*)d_in[4];
    const float* W     = (const float*)d_in[5];
    const float* b     = (const float*)d_in[6];
    float* out = (float*)d_out;

    // workspace: count[N] | slots[N*CAP int2] | h_sum[N*64 f32]
    auto align256 = [](size_t x) { return (x + 255) & ~(size_t)255; };
    char* ws = (char*)d_ws;
    int*  count = (int*)ws;
    int2* slots = (int2*)(ws + align256((size_t)N_NODES * 4));
    float* h_sum = (float*)(ws + align256((size_t)N_NODES * 4)
                               + align256((size_t)N_NODES * CAP * 8));

    hipMemsetAsync(count, 0, (size_t)N_NODES * 4, stream);

    k1_score_bucket<<<N_EDGES / 16, 256, 0, stream>>>(
        (const vf4*)h_src, (const vf4*)e, src, dst, count, slots);
    k2_agg<<<N_NODES / 16, 256, 0, stream>>>(
        (const vf4*)h_src, count, slots, (vf4*)h_sum);
    k3_linear<<<(N_NODES + 15) / 16, 256, 0, stream>>>(
        (const vf4*)h_dst, (const vf4*)h_sum, W, b, out);
}